// Round 5
// baseline (121.129 us; speedup 1.0000x reference)
//
#include <hip/hip_runtime.h>
#include <hip/hip_cooperative_groups.h>
#include <math.h>

namespace cg = cooperative_groups;

// Problem constants (match reference).
#define B_SZ   2048
#define K_MAIN 511
#define K_OUT  512
#define D_SZ   64

// Workspace layout (floats):
//   coef  [0 .. K_MAIN*D_SZ)  = (softmax(logits)+1e-10)*exp(clip(ld)) per (k,d)
//   betas [K_MAIN*D_SZ .. +K_MAIN)
#define WS_COEF  0
#define WS_BETAS (K_MAIN * D_SZ)

#define GRID_BLOCKS 1024   // 4 blocks/CU x 256 CU -> co-resident, cooperative-legal

typedef float f4v __attribute__((ext_vector_type(4)));

__device__ __forceinline__ float softplus_clip(float x) {
    float sp = (x > 20.f) ? x : log1pf(expf(x));
    return fminf(fmaxf(sp, 0.f), 10.f);
}

// Single fused cooperative kernel.
// Phase 1: global waves 0..510 compute coef row k (+beta); waves 511..542 fill
//          the null output column (64 rows each).
// grid.sync()
// Phase 2: grid-stride streaming reduction over vals (x4 unrolled, plain loads).
__global__ void __launch_bounds__(256, 4)
fused_kernel(const float* __restrict__ vals,             // (B, K_MAIN, D)
             const float* __restrict__ log_density,      // (K_MAIN, D)
             const float* __restrict__ logits,           // (K_MAIN, D)
             const float* __restrict__ beta_raw,         // (K_MAIN,)
             const float* __restrict__ null_vals,        // (B,)
             const float* __restrict__ null_log_density, // (D,)
             const float* __restrict__ null_logits,      // (D,)
             const float* __restrict__ null_beta_raw,    // (1,)
             float* __restrict__ ws,
             float* __restrict__ out) {                  // (B, K_OUT)
    const unsigned tid   = blockIdx.x * blockDim.x + threadIdx.x;
    const unsigned lane  = threadIdx.x & 63u;
    const unsigned gwave = tid >> 6;

    // ---------------- Phase 1: tiny precompute ----------------
    if (gwave < K_MAIN) {
        const unsigned k = gwave;
        float lg = logits[k * D_SZ + lane];
        float m = lg;
        #pragma unroll
        for (int off = 1; off < 64; off <<= 1) m = fmaxf(m, __shfl_xor(m, off));
        float e = expf(lg - m);
        float s = e;
        #pragma unroll
        for (int off = 1; off < 64; off <<= 1) s += __shfl_xor(s, off);
        float w = e / s;                                   // softmax
        float ld = fminf(fmaxf(log_density[k * D_SZ + lane], -10.f), 0.f);
        // exp(log(w+1e-10) + ld) == (w+1e-10)*exp(ld); exp(M) folded exactly.
        ws[WS_COEF + k * D_SZ + lane] = (w + 1e-10f) * expf(ld);
        if (lane == 0) {
            ws[WS_BETAS + k] = softplus_clip(beta_raw[k]);
        }
    } else if (gwave < K_MAIN + B_SZ / 64) {               // waves 511..542
        float lg = null_logits[lane];
        float m = lg;
        #pragma unroll
        for (int off = 1; off < 64; off <<= 1) m = fmaxf(m, __shfl_xor(m, off));
        float e = expf(lg - m);
        float s = e;
        #pragma unroll
        for (int off = 1; off < 64; off <<= 1) s += __shfl_xor(s, off);
        // every lane recomputes softmax[0] from the broadcast scalar
        float w0 = expf(null_logits[0] - m) / s;
        float ld0 = fminf(fmaxf(null_log_density[0], -10.f), 0.f);
        float c_null = (w0 + 1e-10f) * expf(ld0);
        float nbeta  = softplus_clip(null_beta_raw[0]);
        const unsigned b = (gwave - K_MAIN) * 64 + lane;
        out[(size_t)b * K_OUT + K_MAIN] = c_null * null_vals[b] - nbeta;
    }

    cg::this_grid().sync();

    // ---------------- Phase 2: streaming reduction ----------------
    const float* __restrict__ coef  = ws + WS_COEF;
    const float* __restrict__ betas = ws + WS_BETAS;

    const unsigned nwaves = (gridDim.x * blockDim.x) >> 6;   // 4096
    const unsigned sub    = lane >> 4;          // 0..3 : row within chunk
    const unsigned d0     = (lane & 15u) << 2;  // 0,4,...,60

    const unsigned total_rows = B_SZ * K_MAIN;   // 1,046,528 (divisible by 16)
    const unsigned nquads     = total_rows >> 4; // 65,408 groups of 16 rows

    for (unsigned q = gwave; q < nquads; q += nwaves) {
        const unsigned r0 = (q << 4) + sub;      // rows r0, r0+4, r0+8, r0+12

        // 4 independent loads, issued back-to-back
        const f4v v0 = *reinterpret_cast<const f4v*>(vals + (size_t)r0 * D_SZ + d0);
        const f4v v1 = *reinterpret_cast<const f4v*>(vals + (size_t)(r0 + 4) * D_SZ + d0);
        const f4v v2 = *reinterpret_cast<const f4v*>(vals + (size_t)(r0 + 8) * D_SZ + d0);
        const f4v v3 = *reinterpret_cast<const f4v*>(vals + (size_t)(r0 + 12) * D_SZ + d0);

        // k/b for the 4 rows: one div-mod + incremental branchless wrap
        unsigned k0 = r0 % K_MAIN;               // magic-mul
        unsigned b0 = r0 / K_MAIN;
        unsigned k1 = k0 + 4, b1 = b0; if (k1 >= K_MAIN) { k1 -= K_MAIN; ++b1; }
        unsigned k2 = k1 + 4, b2 = b1; if (k2 >= K_MAIN) { k2 -= K_MAIN; ++b2; }
        unsigned k3 = k2 + 4, b3 = b2; if (k3 >= K_MAIN) { k3 -= K_MAIN; ++b3; }

        const f4v c0 = *reinterpret_cast<const f4v*>(coef + (size_t)k0 * D_SZ + d0);
        const f4v c1 = *reinterpret_cast<const f4v*>(coef + (size_t)k1 * D_SZ + d0);
        const f4v c2 = *reinterpret_cast<const f4v*>(coef + (size_t)k2 * D_SZ + d0);
        const f4v c3 = *reinterpret_cast<const f4v*>(coef + (size_t)k3 * D_SZ + d0);

        float p0 = v0.x * c0.x + v0.y * c0.y + v0.z * c0.z + v0.w * c0.w;
        float p1 = v1.x * c1.x + v1.y * c1.y + v1.z * c1.z + v1.w * c1.w;
        float p2 = v2.x * c2.x + v2.y * c2.y + v2.z * c2.z + v2.w * c2.w;
        float p3 = v3.x * c3.x + v3.y * c3.y + v3.z * c3.z + v3.w * c3.w;

        p0 += __shfl_xor(p0, 1);  p1 += __shfl_xor(p1, 1);
        p2 += __shfl_xor(p2, 1);  p3 += __shfl_xor(p3, 1);
        p0 += __shfl_xor(p0, 2);  p1 += __shfl_xor(p1, 2);
        p2 += __shfl_xor(p2, 2);  p3 += __shfl_xor(p3, 2);
        p0 += __shfl_xor(p0, 4);  p1 += __shfl_xor(p1, 4);
        p2 += __shfl_xor(p2, 4);  p3 += __shfl_xor(p3, 4);
        p0 += __shfl_xor(p0, 8);  p1 += __shfl_xor(p1, 8);
        p2 += __shfl_xor(p2, 8);  p3 += __shfl_xor(p3, 8);

        if ((lane & 15u) == 0u) {
            out[(size_t)b0 * K_OUT + k0] = p0 - betas[k0];
            out[(size_t)b1 * K_OUT + k1] = p1 - betas[k1];
            out[(size_t)b2 * K_OUT + k2] = p2 - betas[k2];
            out[(size_t)b3 * K_OUT + k3] = p3 - betas[k3];
        }
    }
}

extern "C" void kernel_launch(void* const* d_in, const int* in_sizes, int n_in,
                              void* d_out, int out_size, void* d_ws, size_t ws_size,
                              hipStream_t stream) {
    const float* vals             = (const float*)d_in[0];
    const float* log_density      = (const float*)d_in[1];
    const float* logits           = (const float*)d_in[2];
    const float* beta_raw         = (const float*)d_in[3];
    const float* null_vals        = (const float*)d_in[4];
    const float* null_log_density = (const float*)d_in[5];
    const float* null_logits      = (const float*)d_in[6];
    const float* null_beta_raw    = (const float*)d_in[7];

    float* out = (float*)d_out;
    float* ws  = (float*)d_ws;

    void* args[] = {
        (void*)&vals, (void*)&log_density, (void*)&logits, (void*)&beta_raw,
        (void*)&null_vals, (void*)&null_log_density, (void*)&null_logits,
        (void*)&null_beta_raw, (void*)&ws, (void*)&out,
    };
    hipLaunchCooperativeKernel((void*)fused_kernel, dim3(GRID_BLOCKS), dim3(256),
                               args, 0, stream);
}

// Round 6
// 116.464 us; speedup vs baseline: 1.0401x; 1.0401x over previous
//
#include <hip/hip_runtime.h>
#include <math.h>

// Problem constants (match reference).
#define B_SZ   2048
#define K_MAIN 511
#define K_OUT  512
#define D_SZ   64

typedef float f4v __attribute__((ext_vector_type(4)));

__device__ __forceinline__ float softplus_clip(float x) {
    float sp = (x > 20.f) ? x : log1pf(expf(x));
    return fminf(fmaxf(sp, 0.f), 10.f);
}

// Per-row weighted reduction with on-the-fly softmax/coef, within a 16-lane
// group (lanes hold d0..d0+3 each; the group holds the full 64-wide row).
// Returns the group-reduced weighted sum (valid in all 16 lanes).
__device__ __forceinline__ float row_reduce(f4v v, f4v g, f4v l) {
    // group max of logits row (exact, order-independent)
    float m = fmaxf(fmaxf(g.x, g.y), fmaxf(g.z, g.w));
    m = fmaxf(m, __shfl_xor(m, 1));
    m = fmaxf(m, __shfl_xor(m, 2));
    m = fmaxf(m, __shfl_xor(m, 4));
    m = fmaxf(m, __shfl_xor(m, 8));
    float e0 = expf(g.x - m), e1 = expf(g.y - m);
    float e2 = expf(g.z - m), e3 = expf(g.w - m);
    float s = (e0 + e1) + (e2 + e3);
    s += __shfl_xor(s, 1);
    s += __shfl_xor(s, 2);
    s += __shfl_xor(s, 4);
    s += __shfl_xor(s, 8);
    const float inv = 1.f / s;
    // coef = (softmax + 1e-10) * exp(clip(log_density)); exp(M) folded exactly
    float c0 = (e0 * inv + 1e-10f) * expf(fminf(fmaxf(l.x, -10.f), 0.f));
    float c1 = (e1 * inv + 1e-10f) * expf(fminf(fmaxf(l.y, -10.f), 0.f));
    float c2 = (e2 * inv + 1e-10f) * expf(fminf(fmaxf(l.z, -10.f), 0.f));
    float c3 = (e3 * inv + 1e-10f) * expf(fminf(fmaxf(l.w, -10.f), 0.f));
    float p = v.x * c0 + v.y * c1 + v.z * c2 + v.w * c3;
    p += __shfl_xor(p, 1);
    p += __shfl_xor(p, 2);
    p += __shfl_xor(p, 4);
    p += __shfl_xor(p, 8);
    return p;
}

// Single fused kernel, one dispatch, no workspace.
// Waves 0..31: fill the null output column (independent of everything else).
// All waves: grid-stride x4-unrolled streaming reduction over vals with
// inline softmax/coef recompute (logits/log_density are L2-resident).
__global__ void __launch_bounds__(256)
fused_kernel(const float* __restrict__ vals,             // (B, K_MAIN, D)
             const float* __restrict__ log_density,      // (K_MAIN, D)
             const float* __restrict__ logits,           // (K_MAIN, D)
             const float* __restrict__ beta_raw,         // (K_MAIN,)
             const float* __restrict__ null_vals,        // (B,)
             const float* __restrict__ null_log_density, // (D,)
             const float* __restrict__ null_logits,      // (D,)
             const float* __restrict__ null_beta_raw,    // (1,)
             float* __restrict__ out) {                  // (B, K_OUT)
    const unsigned tid    = blockIdx.x * blockDim.x + threadIdx.x;
    const unsigned lane   = threadIdx.x & 63u;
    const unsigned gwave  = tid >> 6;
    const unsigned nwaves = (gridDim.x * blockDim.x) >> 6;   // 16384

    // ---- null column: waves 0..31, 64 rows each (no sync needed) ----
    if (gwave < B_SZ / 64) {
        float lg = null_logits[lane];
        float m = lg;
        #pragma unroll
        for (int off = 1; off < 64; off <<= 1) m = fmaxf(m, __shfl_xor(m, off));
        float e = expf(lg - m);
        float s = e;
        #pragma unroll
        for (int off = 1; off < 64; off <<= 1) s += __shfl_xor(s, off);
        float w0 = expf(null_logits[0] - m) / s;   // softmax[0], uniform
        float ld0 = fminf(fmaxf(null_log_density[0], -10.f), 0.f);
        float c_null = (w0 + 1e-10f) * expf(ld0);
        float nbeta  = softplus_clip(null_beta_raw[0]);
        const unsigned b = gwave * 64 + lane;
        out[(size_t)b * K_OUT + K_MAIN] = c_null * null_vals[b] - nbeta;
    }

    // ---- main streaming loop ----
    const unsigned sub = lane >> 4;          // 0..3 : row within chunk of 4
    const unsigned d0  = (lane & 15u) << 2;  // 0,4,...,60

    const unsigned total_rows = B_SZ * K_MAIN;   // 1,046,528 (divisible by 16)
    const unsigned nquads     = total_rows >> 4; // 65,408 groups of 16 rows

    for (unsigned q = gwave; q < nquads; q += nwaves) {
        const unsigned r0 = (q << 4) + sub;      // rows r0, r0+4, r0+8, r0+12

        // k/b for the 4 rows: one div-mod (magic-mul) + branchless wrap
        unsigned k0 = r0 % K_MAIN;
        unsigned b0 = r0 / K_MAIN;
        unsigned k1 = k0 + 4, b1 = b0; if (k1 >= K_MAIN) { k1 -= K_MAIN; ++b1; }
        unsigned k2 = k1 + 4, b2 = b1; if (k2 >= K_MAIN) { k2 -= K_MAIN; ++b2; }
        unsigned k3 = k2 + 4, b3 = b2; if (k3 >= K_MAIN) { k3 -= K_MAIN; ++b3; }

        // issue all loads back-to-back: 4 vals (HBM stream) + 4 logits +
        // 4 log_density + 4 beta_raw (all L2-resident tables)
        const f4v v0 = *reinterpret_cast<const f4v*>(vals + (size_t)r0 * D_SZ + d0);
        const f4v v1 = *reinterpret_cast<const f4v*>(vals + (size_t)(r0 + 4) * D_SZ + d0);
        const f4v v2 = *reinterpret_cast<const f4v*>(vals + (size_t)(r0 + 8) * D_SZ + d0);
        const f4v v3 = *reinterpret_cast<const f4v*>(vals + (size_t)(r0 + 12) * D_SZ + d0);

        const f4v g0 = *reinterpret_cast<const f4v*>(logits + (size_t)k0 * D_SZ + d0);
        const f4v g1 = *reinterpret_cast<const f4v*>(logits + (size_t)k1 * D_SZ + d0);
        const f4v g2 = *reinterpret_cast<const f4v*>(logits + (size_t)k2 * D_SZ + d0);
        const f4v g3 = *reinterpret_cast<const f4v*>(logits + (size_t)k3 * D_SZ + d0);

        const f4v l0 = *reinterpret_cast<const f4v*>(log_density + (size_t)k0 * D_SZ + d0);
        const f4v l1 = *reinterpret_cast<const f4v*>(log_density + (size_t)k1 * D_SZ + d0);
        const f4v l2 = *reinterpret_cast<const f4v*>(log_density + (size_t)k2 * D_SZ + d0);
        const f4v l3 = *reinterpret_cast<const f4v*>(log_density + (size_t)k3 * D_SZ + d0);

        const float br0 = beta_raw[k0];
        const float br1 = beta_raw[k1];
        const float br2 = beta_raw[k2];
        const float br3 = beta_raw[k3];

        const float p0 = row_reduce(v0, g0, l0);
        const float p1 = row_reduce(v1, g1, l1);
        const float p2 = row_reduce(v2, g2, l2);
        const float p3 = row_reduce(v3, g3, l3);

        if ((lane & 15u) == 0u) {
            out[(size_t)b0 * K_OUT + k0] = p0 - softplus_clip(br0);
            out[(size_t)b1 * K_OUT + k1] = p1 - softplus_clip(br1);
            out[(size_t)b2 * K_OUT + k2] = p2 - softplus_clip(br2);
            out[(size_t)b3 * K_OUT + k3] = p3 - softplus_clip(br3);
        }
    }
}

extern "C" void kernel_launch(void* const* d_in, const int* in_sizes, int n_in,
                              void* d_out, int out_size, void* d_ws, size_t ws_size,
                              hipStream_t stream) {
    const float* vals             = (const float*)d_in[0];
    const float* log_density      = (const float*)d_in[1];
    const float* logits           = (const float*)d_in[2];
    const float* beta_raw         = (const float*)d_in[3];
    const float* null_vals        = (const float*)d_in[4];
    const float* null_log_density = (const float*)d_in[5];
    const float* null_logits      = (const float*)d_in[6];
    const float* null_beta_raw    = (const float*)d_in[7];

    float* out = (float*)d_out;

    fused_kernel<<<4096, 256, 0, stream>>>(vals, log_density, logits, beta_raw,
                                           null_vals, null_log_density,
                                           null_logits, null_beta_raw, out);
}

// Round 7
// 45.841 us; speedup vs baseline: 2.6424x; 2.5406x over previous
//
#include <hip/hip_runtime.h>
#include <math.h>

// Problem constants (match reference).
#define B_SZ   2048
#define K_MAIN 511
#define K_OUT  512
#define D_SZ   64

#define KTILES 32                         // 32 tiles x 16 k = 512 k-slots (slot 511 idle)
#define BCHUNK 32                         // b's per block
#define NBLK_MAIN (KTILES * (B_SZ / BCHUNK))   // 32 * 64 = 2048
#define NBLK_NULL (B_SZ / 256)                 // 8

typedef float f4v __attribute__((ext_vector_type(4)));

__device__ __forceinline__ float softplus_clip(float x) {
    float sp = (x > 20.f) ? x : log1pf(expf(x));
    return fminf(fmaxf(sp, 0.f), 10.f);
}

// Single fused kernel, one dispatch, no workspace, no sync.
// Main blocks (0..2047): block owns (k_tile of 16 k, b_chunk of 32 b).
//   Each 16-lane group holds ONE k: computes coef/beta once into registers
//   (8 __expf, amortized over 32 rows), then streams b with x4-unrolled
//   independent float4 loads. Rows (b, k0..k0+15) read by the block are
//   4KB contiguous; out-writes for one b hit a single 64B line.
// Null blocks (2048..2055): fill the null output column.
__global__ void __launch_bounds__(256)
fused_kernel(const float* __restrict__ vals,             // (B, K_MAIN, D)
             const float* __restrict__ log_density,      // (K_MAIN, D)
             const float* __restrict__ logits,           // (K_MAIN, D)
             const float* __restrict__ beta_raw,         // (K_MAIN,)
             const float* __restrict__ null_vals,        // (B,)
             const float* __restrict__ null_log_density, // (D,)
             const float* __restrict__ null_logits,      // (D,)
             const float* __restrict__ null_beta_raw,    // (1,)
             float* __restrict__ out) {                  // (B, K_OUT)
    const unsigned tid  = threadIdx.x;
    const unsigned bid  = blockIdx.x;

    if (bid >= NBLK_MAIN) {
        // ---- null column: 8 blocks x 4 waves x 64 lanes = 2048 rows ----
        const unsigned lane = tid & 63u;
        float lg = null_logits[lane];
        float m = lg;
        #pragma unroll
        for (int off = 1; off < 64; off <<= 1) m = fmaxf(m, __shfl_xor(m, off));
        float e = expf(lg - m);
        float s = e;
        #pragma unroll
        for (int off = 1; off < 64; off <<= 1) s += __shfl_xor(s, off);
        float w0 = expf(null_logits[0] - m) / s;   // softmax[0], wave-uniform
        float ld0 = fminf(fmaxf(null_log_density[0], -10.f), 0.f);
        float c_null = (w0 + 1e-10f) * expf(ld0);
        float nbeta  = softplus_clip(null_beta_raw[0]);
        const unsigned b = ((bid - NBLK_MAIN) * 4 + (tid >> 6)) * 64 + lane;
        out[(size_t)b * K_OUT + K_MAIN] = c_null * null_vals[b] - nbeta;
        return;
    }

    // ---- main path ----
    const unsigned grp = tid >> 4;          // 0..15 : group within block
    const unsigned gl  = tid & 15u;         // lane within group
    const unsigned kt  = bid % KTILES;      // consecutive blocks sweep k-tiles
    const unsigned bc  = bid / KTILES;
    const unsigned k   = kt * 16 + grp;     // 0..511 (511 = idle slot)
    const unsigned d0  = gl << 2;           // 0,4,...,60

    if (k >= K_MAIN) return;                // idle 16-lane group (1/512 waste)

    // --- per-k coefficients, once, into registers ---
    f4v c;
    float beta;
    {
        const f4v g = *reinterpret_cast<const f4v*>(logits + (size_t)k * D_SZ + d0);
        float m = fmaxf(fmaxf(g.x, g.y), fmaxf(g.z, g.w));
        m = fmaxf(m, __shfl_xor(m, 1));
        m = fmaxf(m, __shfl_xor(m, 2));
        m = fmaxf(m, __shfl_xor(m, 4));
        m = fmaxf(m, __shfl_xor(m, 8));     // group max (exact)
        float e0 = __expf(g.x - m), e1 = __expf(g.y - m);
        float e2 = __expf(g.z - m), e3 = __expf(g.w - m);
        float s = (e0 + e1) + (e2 + e3);
        s += __shfl_xor(s, 1);
        s += __shfl_xor(s, 2);
        s += __shfl_xor(s, 4);
        s += __shfl_xor(s, 8);
        const float inv = 1.f / s;
        const f4v l = *reinterpret_cast<const f4v*>(log_density + (size_t)k * D_SZ + d0);
        // coef = (softmax + 1e-10) * exp(clip(ld)); exp(M) folded exactly.
        c.x = (e0 * inv + 1e-10f) * __expf(fminf(fmaxf(l.x, -10.f), 0.f));
        c.y = (e1 * inv + 1e-10f) * __expf(fminf(fmaxf(l.y, -10.f), 0.f));
        c.z = (e2 * inv + 1e-10f) * __expf(fminf(fmaxf(l.z, -10.f), 0.f));
        c.w = (e3 * inv + 1e-10f) * __expf(fminf(fmaxf(l.w, -10.f), 0.f));
        beta = softplus_clip(beta_raw[k]);
    }

    // --- stream 32 b's, 4 at a time (4 independent 16B loads/lane) ---
    const unsigned b0 = bc * BCHUNK;
    const size_t  bstride = (size_t)K_MAIN * D_SZ;   // floats between b's
    const float* __restrict__ vrow = vals + ((size_t)b0 * K_MAIN + k) * D_SZ + d0;

    for (unsigned i = 0; i < BCHUNK / 4; ++i) {
        const float* p = vrow + (size_t)(i * 4) * bstride;
        const f4v v0 = *reinterpret_cast<const f4v*>(p);
        const f4v v1 = *reinterpret_cast<const f4v*>(p + bstride);
        const f4v v2 = *reinterpret_cast<const f4v*>(p + 2 * bstride);
        const f4v v3 = *reinterpret_cast<const f4v*>(p + 3 * bstride);

        float q0 = v0.x * c.x + v0.y * c.y + v0.z * c.z + v0.w * c.w;
        float q1 = v1.x * c.x + v1.y * c.y + v1.z * c.z + v1.w * c.w;
        float q2 = v2.x * c.x + v2.y * c.y + v2.z * c.z + v2.w * c.w;
        float q3 = v3.x * c.x + v3.y * c.y + v3.z * c.z + v3.w * c.w;

        q0 += __shfl_xor(q0, 1);  q1 += __shfl_xor(q1, 1);
        q2 += __shfl_xor(q2, 1);  q3 += __shfl_xor(q3, 1);
        q0 += __shfl_xor(q0, 2);  q1 += __shfl_xor(q1, 2);
        q2 += __shfl_xor(q2, 2);  q3 += __shfl_xor(q3, 2);
        q0 += __shfl_xor(q0, 4);  q1 += __shfl_xor(q1, 4);
        q2 += __shfl_xor(q2, 4);  q3 += __shfl_xor(q3, 4);
        q0 += __shfl_xor(q0, 8);  q1 += __shfl_xor(q1, 8);
        q2 += __shfl_xor(q2, 8);  q3 += __shfl_xor(q3, 8);

        if (gl == 0) {
            const unsigned b = b0 + i * 4;
            out[(size_t)b       * K_OUT + k] = q0 - beta;
            out[(size_t)(b + 1) * K_OUT + k] = q1 - beta;
            out[(size_t)(b + 2) * K_OUT + k] = q2 - beta;
            out[(size_t)(b + 3) * K_OUT + k] = q3 - beta;
        }
    }
}

extern "C" void kernel_launch(void* const* d_in, const int* in_sizes, int n_in,
                              void* d_out, int out_size, void* d_ws, size_t ws_size,
                              hipStream_t stream) {
    const float* vals             = (const float*)d_in[0];
    const float* log_density      = (const float*)d_in[1];
    const float* logits           = (const float*)d_in[2];
    const float* beta_raw         = (const float*)d_in[3];
    const float* null_vals        = (const float*)d_in[4];
    const float* null_log_density = (const float*)d_in[5];
    const float* null_logits      = (const float*)d_in[6];
    const float* null_beta_raw    = (const float*)d_in[7];

    float* out = (float*)d_out;

    fused_kernel<<<NBLK_MAIN + NBLK_NULL, 256, 0, stream>>>(
        vals, log_density, logits, beta_raw,
        null_vals, null_log_density, null_logits, null_beta_raw, out);
}

// Round 8
// 45.373 us; speedup vs baseline: 2.6696x; 1.0103x over previous
//
#include <hip/hip_runtime.h>
#include <math.h>

// Problem constants (match reference).
#define B_SZ   2048
#define K_MAIN 511
#define K_OUT  512
#define D_SZ   64

#define KTILES 32                         // 32 tiles x 16 k = 512 k-slots (slot 511 idle)
#define BCHUNK 32                         // b's per block
#define NBLK_MAIN (KTILES * (B_SZ / BCHUNK))   // 32 * 64 = 2048
#define NBLK_NULL (B_SZ / 256)                 // 8

typedef float f4v __attribute__((ext_vector_type(4)));

__device__ __forceinline__ float softplus_clip(float x) {
    float sp = (x > 20.f) ? x : log1pf(expf(x));
    return fminf(fmaxf(sp, 0.f), 10.f);
}

// Single fused kernel, one dispatch, no workspace, no sync.
// Main blocks (0..2047): block owns (k_tile of 16 k, b_chunk of 32 b).
//   Each 16-lane group holds ONE k: computes coef/beta once into registers
//   (8 __expf, amortized over 32 rows), then streams b with x8-unrolled
//   independent float4 loads (8 in flight per lane).
// Null blocks (2048..2055): fill the null output column.
__global__ void __launch_bounds__(256)
fused_kernel(const float* __restrict__ vals,             // (B, K_MAIN, D)
             const float* __restrict__ log_density,      // (K_MAIN, D)
             const float* __restrict__ logits,           // (K_MAIN, D)
             const float* __restrict__ beta_raw,         // (K_MAIN,)
             const float* __restrict__ null_vals,        // (B,)
             const float* __restrict__ null_log_density, // (D,)
             const float* __restrict__ null_logits,      // (D,)
             const float* __restrict__ null_beta_raw,    // (1,)
             float* __restrict__ out) {                  // (B, K_OUT)
    const unsigned tid  = threadIdx.x;
    const unsigned bid  = blockIdx.x;

    if (bid >= NBLK_MAIN) {
        // ---- null column: 8 blocks x 4 waves x 64 lanes = 2048 rows ----
        const unsigned lane = tid & 63u;
        float lg = null_logits[lane];
        float m = lg;
        #pragma unroll
        for (int off = 1; off < 64; off <<= 1) m = fmaxf(m, __shfl_xor(m, off));
        float e = expf(lg - m);
        float s = e;
        #pragma unroll
        for (int off = 1; off < 64; off <<= 1) s += __shfl_xor(s, off);
        float w0 = expf(null_logits[0] - m) / s;   // softmax[0], wave-uniform
        float ld0 = fminf(fmaxf(null_log_density[0], -10.f), 0.f);
        float c_null = (w0 + 1e-10f) * expf(ld0);
        float nbeta  = softplus_clip(null_beta_raw[0]);
        const unsigned b = ((bid - NBLK_MAIN) * 4 + (tid >> 6)) * 64 + lane;
        out[(size_t)b * K_OUT + K_MAIN] = c_null * null_vals[b] - nbeta;
        return;
    }

    // ---- main path ----
    const unsigned grp = tid >> 4;          // 0..15 : group within block
    const unsigned gl  = tid & 15u;         // lane within group
    const unsigned kt  = bid % KTILES;      // consecutive blocks sweep k-tiles
    const unsigned bc  = bid / KTILES;
    const unsigned k   = kt * 16 + grp;     // 0..511 (511 = idle slot)
    const unsigned d0  = gl << 2;           // 0,4,...,60

    if (k >= K_MAIN) return;                // idle 16-lane group (1/512 waste)

    // --- per-k coefficients, once, into registers ---
    f4v c;
    float beta;
    {
        const f4v g = *reinterpret_cast<const f4v*>(logits + (size_t)k * D_SZ + d0);
        float m = fmaxf(fmaxf(g.x, g.y), fmaxf(g.z, g.w));
        m = fmaxf(m, __shfl_xor(m, 1));
        m = fmaxf(m, __shfl_xor(m, 2));
        m = fmaxf(m, __shfl_xor(m, 4));
        m = fmaxf(m, __shfl_xor(m, 8));     // group max (exact)
        float e0 = __expf(g.x - m), e1 = __expf(g.y - m);
        float e2 = __expf(g.z - m), e3 = __expf(g.w - m);
        float s = (e0 + e1) + (e2 + e3);
        s += __shfl_xor(s, 1);
        s += __shfl_xor(s, 2);
        s += __shfl_xor(s, 4);
        s += __shfl_xor(s, 8);
        const float inv = 1.f / s;
        const f4v l = *reinterpret_cast<const f4v*>(log_density + (size_t)k * D_SZ + d0);
        // coef = (softmax + 1e-10) * exp(clip(ld)); exp(M) folded exactly.
        c.x = (e0 * inv + 1e-10f) * __expf(fminf(fmaxf(l.x, -10.f), 0.f));
        c.y = (e1 * inv + 1e-10f) * __expf(fminf(fmaxf(l.y, -10.f), 0.f));
        c.z = (e2 * inv + 1e-10f) * __expf(fminf(fmaxf(l.z, -10.f), 0.f));
        c.w = (e3 * inv + 1e-10f) * __expf(fminf(fmaxf(l.w, -10.f), 0.f));
        beta = softplus_clip(beta_raw[k]);
    }

    // --- stream 32 b's, 8 at a time (8 independent 16B loads/lane) ---
    const unsigned b0 = bc * BCHUNK;
    const size_t  bstride = (size_t)K_MAIN * D_SZ;   // floats between b's
    const float* __restrict__ vrow = vals + ((size_t)b0 * K_MAIN + k) * D_SZ + d0;

    for (unsigned i = 0; i < BCHUNK / 8; ++i) {
        const float* p = vrow + (size_t)(i * 8) * bstride;
        const f4v v0 = *reinterpret_cast<const f4v*>(p);
        const f4v v1 = *reinterpret_cast<const f4v*>(p +     bstride);
        const f4v v2 = *reinterpret_cast<const f4v*>(p + 2 * bstride);
        const f4v v3 = *reinterpret_cast<const f4v*>(p + 3 * bstride);
        const f4v v4 = *reinterpret_cast<const f4v*>(p + 4 * bstride);
        const f4v v5 = *reinterpret_cast<const f4v*>(p + 5 * bstride);
        const f4v v6 = *reinterpret_cast<const f4v*>(p + 6 * bstride);
        const f4v v7 = *reinterpret_cast<const f4v*>(p + 7 * bstride);

        float q0 = v0.x * c.x + v0.y * c.y + v0.z * c.z + v0.w * c.w;
        float q1 = v1.x * c.x + v1.y * c.y + v1.z * c.z + v1.w * c.w;
        float q2 = v2.x * c.x + v2.y * c.y + v2.z * c.z + v2.w * c.w;
        float q3 = v3.x * c.x + v3.y * c.y + v3.z * c.z + v3.w * c.w;
        float q4 = v4.x * c.x + v4.y * c.y + v4.z * c.z + v4.w * c.w;
        float q5 = v5.x * c.x + v5.y * c.y + v5.z * c.z + v5.w * c.w;
        float q6 = v6.x * c.x + v6.y * c.y + v6.z * c.z + v6.w * c.w;
        float q7 = v7.x * c.x + v7.y * c.y + v7.z * c.z + v7.w * c.w;

        q0 += __shfl_xor(q0, 1);  q1 += __shfl_xor(q1, 1);
        q2 += __shfl_xor(q2, 1);  q3 += __shfl_xor(q3, 1);
        q4 += __shfl_xor(q4, 1);  q5 += __shfl_xor(q5, 1);
        q6 += __shfl_xor(q6, 1);  q7 += __shfl_xor(q7, 1);
        q0 += __shfl_xor(q0, 2);  q1 += __shfl_xor(q1, 2);
        q2 += __shfl_xor(q2, 2);  q3 += __shfl_xor(q3, 2);
        q4 += __shfl_xor(q4, 2);  q5 += __shfl_xor(q5, 2);
        q6 += __shfl_xor(q6, 2);  q7 += __shfl_xor(q7, 2);
        q0 += __shfl_xor(q0, 4);  q1 += __shfl_xor(q1, 4);
        q2 += __shfl_xor(q2, 4);  q3 += __shfl_xor(q3, 4);
        q4 += __shfl_xor(q4, 4);  q5 += __shfl_xor(q5, 4);
        q6 += __shfl_xor(q6, 4);  q7 += __shfl_xor(q7, 4);
        q0 += __shfl_xor(q0, 8);  q1 += __shfl_xor(q1, 8);
        q2 += __shfl_xor(q2, 8);  q3 += __shfl_xor(q3, 8);
        q4 += __shfl_xor(q4, 8);  q5 += __shfl_xor(q5, 8);
        q6 += __shfl_xor(q6, 8);  q7 += __shfl_xor(q7, 8);

        if (gl == 0) {
            const unsigned b = b0 + i * 8;
            out[(size_t)b       * K_OUT + k] = q0 - beta;
            out[(size_t)(b + 1) * K_OUT + k] = q1 - beta;
            out[(size_t)(b + 2) * K_OUT + k] = q2 - beta;
            out[(size_t)(b + 3) * K_OUT + k] = q3 - beta;
            out[(size_t)(b + 4) * K_OUT + k] = q4 - beta;
            out[(size_t)(b + 5) * K_OUT + k] = q5 - beta;
            out[(size_t)(b + 6) * K_OUT + k] = q6 - beta;
            out[(size_t)(b + 7) * K_OUT + k] = q7 - beta;
        }
    }
}

extern "C" void kernel_launch(void* const* d_in, const int* in_sizes, int n_in,
                              void* d_out, int out_size, void* d_ws, size_t ws_size,
                              hipStream_t stream) {
    const float* vals             = (const float*)d_in[0];
    const float* log_density      = (const float*)d_in[1];
    const float* logits           = (const float*)d_in[2];
    const float* beta_raw         = (const float*)d_in[3];
    const float* null_vals        = (const float*)d_in[4];
    const float* null_log_density = (const float*)d_in[5];
    const float* null_logits      = (const float*)d_in[6];
    const float* null_beta_raw    = (const float*)d_in[7];

    float* out = (float*)d_out;

    fused_kernel<<<NBLK_MAIN + NBLK_NULL, 256, 0, stream>>>(
        vals, log_density, logits, beta_raw,
        null_vals, null_log_density, null_logits, null_beta_raw, out);
}